// Round 2
// baseline (867.733 us; speedup 1.0000x reference)
//
#include <hip/hip_runtime.h>

// GIN on MI355X. Algebra: segsum(x[src]+ea) = segsum(x[src]) + segsum(ea), and
// segsum(edge_attr@We + be) = segsum(edge_attr)@We + deg*be.
// => edge features read once; per-layer work = CSR gather of x + 2 MFMA GEMMs.
// Runtime dtype sniff: device float tensors may be bf16 or f32; a flag kernel
// detects the layout from x's bit patterns and everything adapts.

typedef unsigned short u16;
typedef unsigned int   u32;

using short8 = __attribute__((ext_vector_type(8))) short;
using f32x4  = __attribute__((ext_vector_type(4))) float;

__device__ __forceinline__ float b2f(u16 u) {
  union { u32 i; float f; } v; v.i = ((u32)u) << 16; return v.f;
}
__device__ __forceinline__ u16 f2b(float f) {
  union { float f; u32 i; } v; v.f = f;
  u32 i = v.i;
  return (u16)((i + 0x7FFFu + ((i >> 16) & 1u)) >> 16); // RNE
}

// ---------- dtype sniff: bf16 stream => ~all 16b words have float-like exponent ----------
__global__ void sniff_kernel(const u16* __restrict__ xu, int* __restrict__ flag) {
  __shared__ int cnt;
  if (threadIdx.x == 0) cnt = 0;
  __syncthreads();
  int c = 0;
  for (int i = threadIdx.x; i < 1024; i += 256) {
    int e = (xu[i] >> 7) & 0xFF;
    if (e >= 100 && e <= 140) c++;
  }
  atomicAdd(&cnt, c);
  __syncthreads();
  if (threadIdx.x == 0) *flag = (cnt >= 820) ? 1 : 0;   // 1 = bf16 layout
}

__global__ void cvt_bf16_kernel(const void* __restrict__ src, u16* __restrict__ dst,
                                int n, const int* __restrict__ flag) {
  int i = blockIdx.x * 256 + threadIdx.x;
  if (i >= n) return;
  if (*flag) dst[i] = ((const u16*)src)[i];
  else       dst[i] = f2b(((const float*)src)[i]);
}

__global__ void cvt_f32_kernel(const void* __restrict__ src, float* __restrict__ dst,
                               int n, const int* __restrict__ flag) {
  int i = blockIdx.x * 256 + threadIdx.x;
  if (i >= n) return;
  if (*flag) dst[i] = b2f(((const u16*)src)[i]);
  else       dst[i] = ((const float*)src)[i];
}

// ---------- CSR build ----------
__global__ void deg_kernel(const int* __restrict__ dst, int* __restrict__ deg, int e) {
  int i = blockIdx.x * 256 + threadIdx.x;
  if (i < e) atomicAdd(&deg[dst[i]], 1);
}

// block-local exclusive scan (256/block) + per-block totals
__global__ void scanA_kernel(const int* __restrict__ deg, int* __restrict__ rowptr,
                             float* __restrict__ invdeg, int* __restrict__ btot, int n) {
  __shared__ int wsum[4];
  int tid = threadIdx.x, lane = tid & 63, wid = tid >> 6;
  int i = blockIdx.x * 256 + tid;
  int v = (i < n) ? deg[i] : 0;
  int incl = v;
  #pragma unroll
  for (int off = 1; off < 64; off <<= 1) {
    int t = __shfl_up(incl, off, 64);
    if (lane >= off) incl += t;
  }
  if (lane == 63) wsum[wid] = incl;
  __syncthreads();
  int woff = 0;
  for (int w = 0; w < wid; ++w) woff += wsum[w];
  if (i < n) {
    rowptr[i] = woff + incl - v;
    invdeg[i] = 1.0f / fmaxf((float)v, 1.0f);
  }
  if (tid == 255) btot[blockIdx.x] = woff + incl;
}

// exclusive scan of block totals (nb <= 256)
__global__ void scanB_kernel(int* __restrict__ btot, int nb) {
  __shared__ int wsum[4];
  int tid = threadIdx.x, lane = tid & 63, wid = tid >> 6;
  int v = (tid < nb) ? btot[tid] : 0;
  int incl = v;
  #pragma unroll
  for (int off = 1; off < 64; off <<= 1) {
    int t = __shfl_up(incl, off, 64);
    if (lane >= off) incl += t;
  }
  if (lane == 63) wsum[wid] = incl;
  __syncthreads();
  int woff = 0;
  for (int w = 0; w < wid; ++w) woff += wsum[w];
  if (tid < nb) btot[tid] = woff + incl - v;
}

__global__ void scanC_kernel(int* __restrict__ rowptr, const int* __restrict__ btot,
                             int n, int e) {
  int i = blockIdx.x * 256 + threadIdx.x;
  if (i < n) rowptr[i] += btot[blockIdx.x];
  if (i == 0) rowptr[n] = e;
}

__global__ void fill_kernel(const int* __restrict__ src, const int* __restrict__ dst,
                            const int* __restrict__ rowptr, int* __restrict__ fillc,
                            int* __restrict__ csr_src, int* __restrict__ csr_eid, int e) {
  int i = blockIdx.x * 256 + threadIdx.x;
  if (i < e) {
    int d = dst[i];
    int p = rowptr[d] + atomicAdd(&fillc[d], 1);
    csr_src[p] = src[i];
    csr_eid[p] = i;
  }
}

// ---------- GEMM: C[M,N] = act(A[M,K] @ W[K,N] + b), bf16 in, fp32 accum ----------
// 256 thr = 4 waves, 64 rows/block, wave = 16-row strip. W^T staged in LDS per K-chunk.
template <int K, int N, int ACT, int FINAL>
__global__ __launch_bounds__(256) void gemm_kernel(const u16* __restrict__ A,
                                                   const u16* __restrict__ W,
                                                   const float* __restrict__ bias,
                                                   void* __restrict__ Cv, int M,
                                                   const int* __restrict__ flag) {
  constexpr int KC = 64;
  constexpr int KCP = KC + 8;        // 144B rows: 16B-aligned, bank-conflict pad
  constexpr int NF = N / 16;
  static_assert(K % KC == 0 && N % 16 == 0, "dims");
  __shared__ u16 WT[N * KCP];

  int tid = threadIdx.x, lane = tid & 63, wid = tid >> 6;
  int row0 = blockIdx.x * 64 + wid * 16;
  int arow = row0 + (lane & 15);
  if (arow >= M) arow = M - 1;       // clamp loads; stores guarded

  f32x4 acc[NF];
  #pragma unroll
  for (int i = 0; i < NF; ++i) acc[i] = (f32x4){0.f, 0.f, 0.f, 0.f};

  for (int kc0 = 0; kc0 < K; kc0 += KC) {
    for (int idx = tid; idx < KC * N; idx += 256) {
      int kk = idx / N, nc = idx % N;
      WT[nc * KCP + kk] = W[(size_t)(kc0 + kk) * N + nc];
    }
    __syncthreads();
    const u16* Ab = A + (size_t)arow * K + kc0 + ((lane >> 4) * 8);
    #pragma unroll
    for (int ks = 0; ks < KC; ks += 32) {
      short8 a = *reinterpret_cast<const short8*>(Ab + ks);
      #pragma unroll
      for (int nf = 0; nf < NF; ++nf) {
        const u16* bp = &WT[(nf * 16 + (lane & 15)) * KCP + ks + ((lane >> 4) * 8)];
        short8 b = *reinterpret_cast<const short8*>(bp);
        acc[nf] = __builtin_amdgcn_mfma_f32_16x16x32_bf16(a, b, acc[nf], 0, 0, 0);
      }
    }
    __syncthreads();
  }

  int isbf = 1;
  if (FINAL) isbf = *flag;
  int crow0 = row0 + ((lane >> 4) * 4);
  #pragma unroll
  for (int nf = 0; nf < NF; ++nf) {
    int col = nf * 16 + (lane & 15);
    float bv = bias[col];
    #pragma unroll
    for (int r = 0; r < 4; ++r) {
      int crow = crow0 + r;
      if (crow < M) {
        float v = acc[nf][r] + bv;
        if (ACT) v = fmaxf(v, 0.f);
        size_t idx = (size_t)crow * N + col;
        if (FINAL && !isbf) ((float*)Cv)[idx] = v;
        else                ((u16*)Cv)[idx]   = f2b(v);
      }
    }
  }
}

// ---------- edge path: seab[n,:] = (segsum(edge_attr)@We + deg*be) * inv_deg ----------
// one wave per node; lane = edge-feature dim (64); dtype-flag-aware edge reads
__global__ __launch_bounds__(256) void sattr_sea_kernel(
    const void* __restrict__ ea, const int* __restrict__ rowptr,
    const int* __restrict__ csr_eid, const u16* __restrict__ edge_Wb,
    const float* __restrict__ edge_bf, const float* __restrict__ invdeg,
    float* __restrict__ seab, int nnodes, const int* __restrict__ flag) {
  __shared__ u16 w[64 * 128];
  int tid = threadIdx.x;
  for (int idx = tid; idx < 64 * 128; idx += 256) w[idx] = edge_Wb[idx];
  __syncthreads();
  int lane = tid & 63, wid = tid >> 6;
  int node = blockIdx.x * 4 + wid;
  if (node >= nnodes) return;
  int isbf = *flag;
  const u16*   eau = (const u16*)ea;
  const float* eaf = (const float*)ea;
  int r0 = rowptr[node], r1 = rowptr[node + 1];
  float acc = 0.f;
  for (int j = r0; j < r1; ++j) {
    size_t off = (size_t)csr_eid[j] * 64 + lane;
    acc += isbf ? b2f(eau[off]) : eaf[off];
  }
  float s0 = 0.f, s1 = 0.f;
  #pragma unroll 4
  for (int k = 0; k < 64; ++k) {
    float ak = __shfl(acc, k, 64);
    u32 wv = *reinterpret_cast<const u32*>(&w[k * 128 + lane * 2]);
    s0 += ak * b2f((u16)(wv & 0xffff));
    s1 += ak * b2f((u16)(wv >> 16));
  }
  float degf = (float)(r1 - r0);
  float iv = invdeg[node];
  seab[(size_t)node * 128 + lane * 2]     = (s0 + degf * edge_bf[lane * 2]) * iv;
  seab[(size_t)node * 128 + lane * 2 + 1] = (s1 + degf * edge_bf[lane * 2 + 1]) * iv;
}

// ---------- per-layer: h0 = (1+eps)*x + segsum(x[src])*inv_deg + seab ----------
__global__ __launch_bounds__(256) void agg_kernel(
    const u16* __restrict__ xcur, const int* __restrict__ rowptr,
    const int* __restrict__ csr_src, const float* __restrict__ invdeg,
    const float* __restrict__ seab, const float* __restrict__ epsf, int l,
    u16* __restrict__ h0, int nnodes) {
  int tid = threadIdx.x, lane = tid & 63, wid = tid >> 6;
  int node = blockIdx.x * 4 + wid;
  if (node >= nnodes) return;
  int r0 = rowptr[node], r1 = rowptr[node + 1];
  float a0 = 0.f, a1 = 0.f;
  for (int j = r0; j < r1; ++j) {
    int s = csr_src[j];
    u32 v = *reinterpret_cast<const u32*>(&xcur[(size_t)s * 128 + lane * 2]);
    a0 += b2f((u16)(v & 0xffff));
    a1 += b2f((u16)(v >> 16));
  }
  float epl = 1.0f + epsf[l];
  float iv = invdeg[node];
  u32 xv = *reinterpret_cast<const u32*>(&xcur[(size_t)node * 128 + lane * 2]);
  float h0v = epl * b2f((u16)(xv & 0xffff)) + a0 * iv + seab[(size_t)node * 128 + lane * 2];
  float h1v = epl * b2f((u16)(xv >> 16))    + a1 * iv + seab[(size_t)node * 128 + lane * 2 + 1];
  u32 packed = (u32)f2b(h0v) | ((u32)f2b(h1v) << 16);
  *reinterpret_cast<u32*>(&h0[(size_t)node * 128 + lane * 2]) = packed;
}

// ---------- launch ----------
extern "C" void kernel_launch(void* const* d_in, const int* in_sizes, int n_in,
                              void* d_out, int out_size, void* d_ws, size_t ws_size,
                              hipStream_t stream) {
  const void* x_in  = d_in[0];
  const void* eattr = d_in[1];
  const int*  eidx  = (const int*)d_in[2];
  const void* nodeW = d_in[3];
  const void* nodeb = d_in[4];
  const void* edgeW = d_in[5];
  const void* edgeb = d_in[6];
  const void* W1    = d_in[7];
  const void* b1    = d_in[8];
  const void* W2    = d_in[9];
  const void* b2    = d_in[10];
  const void* eps   = d_in[11];
  const void* linW  = d_in[12];
  const void* linb  = d_in[13];

  int nn = in_sizes[0] / 128;   // 50000 nodes
  int ne = in_sizes[2] / 2;     // 625000 edges

  char* ws = (char*)d_ws;
  size_t off = 0;
  auto alloc = [&](size_t b) { size_t r = off; off += (b + 255) & ~(size_t)255; return r; };
  int*    flag    = (int*)(ws + alloc(4));
  int*    deg     = (int*)(ws + alloc((size_t)nn * 4));
  int*    fillc   = (int*)(ws + alloc((size_t)nn * 4));
  int*    rowptr  = (int*)(ws + alloc((size_t)(nn + 1) * 4));
  float*  invdeg  = (float*)(ws + alloc((size_t)nn * 4));
  int*    btot    = (int*)(ws + alloc(256 * 4));
  int*    csr_src = (int*)(ws + alloc((size_t)ne * 4));
  int*    csr_eid = (int*)(ws + alloc((size_t)ne * 4));
  float*  seab    = (float*)(ws + alloc((size_t)nn * 128 * 4));
  u16*    xb      = (u16*)(ws + alloc((size_t)nn * 128 * 2));   // converted x
  u16*    xcur    = (u16*)(ws + alloc((size_t)nn * 128 * 2));
  u16*    h0      = (u16*)(ws + alloc((size_t)nn * 128 * 2));
  u16*    tbuf    = (u16*)(ws + alloc((size_t)nn * 256 * 2));
  u16*    nodeWb  = (u16*)(ws + alloc(128 * 128 * 2));
  u16*    edgeWb  = (u16*)(ws + alloc(64 * 128 * 2));
  u16*    W1b     = (u16*)(ws + alloc((size_t)3 * 128 * 256 * 2));
  u16*    W2b     = (u16*)(ws + alloc((size_t)3 * 256 * 128 * 2));
  u16*    linWb   = (u16*)(ws + alloc(128 * 112 * 2));
  float*  nodebf  = (float*)(ws + alloc(128 * 4));
  float*  edgebf  = (float*)(ws + alloc(128 * 4));
  float*  b1f     = (float*)(ws + alloc(3 * 256 * 4));
  float*  b2f_    = (float*)(ws + alloc(3 * 128 * 4));
  float*  epsf    = (float*)(ws + alloc(3 * 4));
  float*  linbf   = (float*)(ws + alloc(112 * 4));

  hipMemsetAsync(deg, 0, (size_t)nn * 4, stream);
  hipMemsetAsync(fillc, 0, (size_t)nn * 4, stream);

  sniff_kernel<<<1, 256, 0, stream>>>((const u16*)x_in, flag);

  auto cvtb = [&](const void* s, u16* d, int n) {
    cvt_bf16_kernel<<<(n + 255) / 256, 256, 0, stream>>>(s, d, n, flag);
  };
  auto cvtf = [&](const void* s, float* d, int n) {
    cvt_f32_kernel<<<(n + 255) / 256, 256, 0, stream>>>(s, d, n, flag);
  };
  cvtb(x_in, xb, nn * 128);
  cvtb(nodeW, nodeWb, 128 * 128);
  cvtb(edgeW, edgeWb, 64 * 128);
  cvtb(W1, W1b, 3 * 128 * 256);
  cvtb(W2, W2b, 3 * 256 * 128);
  cvtb(linW, linWb, 128 * 112);
  cvtf(nodeb, nodebf, 128);
  cvtf(edgeb, edgebf, 128);
  cvtf(b1, b1f, 3 * 256);
  cvtf(b2, b2f_, 3 * 128);
  cvtf(eps, epsf, 3);
  cvtf(linb, linbf, 112);

  int eb = (ne + 255) / 256;
  int nb = (nn + 255) / 256;
  deg_kernel<<<eb, 256, 0, stream>>>(eidx + ne, deg, ne);
  scanA_kernel<<<nb, 256, 0, stream>>>(deg, rowptr, invdeg, btot, nn);
  scanB_kernel<<<1, 256, 0, stream>>>(btot, nb);
  scanC_kernel<<<nb, 256, 0, stream>>>(rowptr, btot, nn, ne);
  fill_kernel<<<eb, 256, 0, stream>>>(eidx, eidx + ne, rowptr, fillc, csr_src, csr_eid, ne);

  int gb = (nn + 63) / 64;
  gemm_kernel<128, 128, 0, 0><<<gb, 256, 0, stream>>>(xb, nodeWb, nodebf, xcur, nn, flag);
  sattr_sea_kernel<<<(nn + 3) / 4, 256, 0, stream>>>(eattr, rowptr, csr_eid, edgeWb, edgebf,
                                                     invdeg, seab, nn, flag);
  for (int l = 0; l < 3; ++l) {
    agg_kernel<<<(nn + 3) / 4, 256, 0, stream>>>(xcur, rowptr, csr_src, invdeg, seab, epsf, l, h0, nn);
    gemm_kernel<128, 256, 1, 0><<<gb, 256, 0, stream>>>(h0, W1b + (size_t)l * 128 * 256,
                                                        b1f + l * 256, tbuf, nn, flag);
    gemm_kernel<256, 128, 1, 0><<<gb, 256, 0, stream>>>(tbuf, W2b + (size_t)l * 256 * 128,
                                                        b2f_ + l * 128, xcur, nn, flag);
  }
  gemm_kernel<128, 112, 0, 1><<<gb, 256, 0, stream>>>(xcur, linWb, linbf, d_out, nn, flag);
}

// Round 3
// 743.652 us; speedup vs baseline: 1.1669x; 1.1669x over previous
//
#include <hip/hip_runtime.h>

// GIN on MI355X. Algebra: segsum(x[src]+ea) = segsum(x[src]) + segsum(ea), and
// segsum(edge_attr@We + be) = segsum(edge_attr)@We + deg*be.
// => edge features read ONCE, streaming (scatter-atomic into sattr[N,64] f32),
//    per-layer work = CSR gather of x + 2 MFMA GEMMs.
// Weights pre-transposed to W^T[N][K] once so GEMM staging is dwordx4 + b128.

typedef unsigned short u16;
typedef unsigned int   u32;

using short8 = __attribute__((ext_vector_type(8))) short;
using f32x4  = __attribute__((ext_vector_type(4))) float;

__device__ __forceinline__ float b2f(u16 u) {
  union { u32 i; float f; } v; v.i = ((u32)u) << 16; return v.f;
}
__device__ __forceinline__ u16 f2b(float f) {
  union { float f; u32 i; } v; v.f = f;
  u32 i = v.i;
  return (u16)((i + 0x7FFFu + ((i >> 16) & 1u)) >> 16); // RNE
}

// ---------- dtype sniff: bf16 stream => ~all 16b words have float-like exponent ----------
__global__ void sniff_kernel(const u16* __restrict__ xu, int* __restrict__ flag) {
  __shared__ int cnt;
  if (threadIdx.x == 0) cnt = 0;
  __syncthreads();
  int c = 0;
  for (int i = threadIdx.x; i < 1024; i += 256) {
    int e = (xu[i] >> 7) & 0xFF;
    if (e >= 100 && e <= 140) c++;
  }
  atomicAdd(&cnt, c);
  __syncthreads();
  if (threadIdx.x == 0) *flag = (cnt >= 820) ? 1 : 0;   // 1 = bf16 layout
}

__global__ void cvt_bf16_kernel(const void* __restrict__ src, u16* __restrict__ dst,
                                int n, const int* __restrict__ flag) {
  int i = blockIdx.x * 256 + threadIdx.x;
  if (i >= n) return;
  if (*flag) dst[i] = ((const u16*)src)[i];
  else       dst[i] = f2b(((const float*)src)[i]);
}

// transpose+cvt: src [L][K][N] -> dst [L][N][K] (bf16)
__global__ void transpose_cvt_kernel(const void* __restrict__ src, u16* __restrict__ dst,
                                     int K, int N, int total, const int* __restrict__ flag) {
  int i = blockIdx.x * 256 + threadIdx.x;
  if (i >= total) return;
  int kn = K * N;
  int l = i / kn, r = i - l * kn;
  int k = r / N, n = r - k * N;
  u16 v = (*flag) ? ((const u16*)src)[i] : f2b(((const float*)src)[i]);
  dst[(size_t)l * kn + n * K + k] = v;
}

struct BiasJobs { const void* src[6]; float* dst[6]; int len[6]; };
__global__ void cvt_bias_kernel(BiasJobs j, const int* __restrict__ flag) {
  int b = blockIdx.x;
  int isbf = *flag;
  for (int i = threadIdx.x; i < j.len[b]; i += 256) {
    j.dst[b][i] = isbf ? b2f(((const u16*)j.src[b])[i]) : ((const float*)j.src[b])[i];
  }
}

// ---------- CSR build ----------
__global__ void deg_kernel(const int* __restrict__ dst, int* __restrict__ deg, int e) {
  int i = blockIdx.x * 256 + threadIdx.x;
  if (i < e) atomicAdd(&deg[dst[i]], 1);
}

__global__ void scanA_kernel(const int* __restrict__ deg, int* __restrict__ rowptr,
                             float* __restrict__ invdeg, int* __restrict__ btot, int n) {
  __shared__ int wsum[4];
  int tid = threadIdx.x, lane = tid & 63, wid = tid >> 6;
  int i = blockIdx.x * 256 + tid;
  int v = (i < n) ? deg[i] : 0;
  int incl = v;
  #pragma unroll
  for (int off = 1; off < 64; off <<= 1) {
    int t = __shfl_up(incl, off, 64);
    if (lane >= off) incl += t;
  }
  if (lane == 63) wsum[wid] = incl;
  __syncthreads();
  int woff = 0;
  for (int w = 0; w < wid; ++w) woff += wsum[w];
  if (i < n) {
    rowptr[i] = woff + incl - v;
    invdeg[i] = 1.0f / fmaxf((float)v, 1.0f);
  }
  if (tid == 255) btot[blockIdx.x] = woff + incl;
}

__global__ void scanB_kernel(int* __restrict__ btot, int nb) {
  __shared__ int wsum[4];
  int tid = threadIdx.x, lane = tid & 63, wid = tid >> 6;
  int v = (tid < nb) ? btot[tid] : 0;
  int incl = v;
  #pragma unroll
  for (int off = 1; off < 64; off <<= 1) {
    int t = __shfl_up(incl, off, 64);
    if (lane >= off) incl += t;
  }
  if (lane == 63) wsum[wid] = incl;
  __syncthreads();
  int woff = 0;
  for (int w = 0; w < wid; ++w) woff += wsum[w];
  if (tid < nb) btot[tid] = woff + incl - v;
}

__global__ void scanC_kernel(int* __restrict__ rowptr, const int* __restrict__ btot,
                             int n, int e) {
  int i = blockIdx.x * 256 + threadIdx.x;
  if (i < n) rowptr[i] += btot[blockIdx.x];
  if (i == 0) rowptr[n] = e;
}

__global__ void fill_kernel(const int* __restrict__ src, const int* __restrict__ dst,
                            const int* __restrict__ rowptr, int* __restrict__ fillc,
                            int* __restrict__ csr_src, int e) {
  int i = blockIdx.x * 256 + threadIdx.x;
  if (i < e) {
    int d = dst[i];
    int p = rowptr[d] + atomicAdd(&fillc[d], 1);
    csr_src[p] = src[i];
  }
}

// ---------- edge scatter: sattr[dst][0:64] += edge_attr[e][0:64], streaming ----------
__global__ __launch_bounds__(256) void scatter_kernel(
    const void* __restrict__ ea, const int* __restrict__ dst,
    float* __restrict__ sattr, int e, const int* __restrict__ flag) {
  int eg = blockIdx.x * 4 + (threadIdx.x >> 6);
  int lane = threadIdx.x & 63;
  if (eg >= e) return;
  int d = dst[eg];
  float v;
  if (*flag) v = b2f(((const u16*)ea)[(size_t)eg * 64 + lane]);
  else       v = ((const float*)ea)[(size_t)eg * 64 + lane];
  atomicAdd(&sattr[(size_t)d * 64 + lane], v);
}

// ---------- GEMM: C[M,N] = epilogue(A[M,K] @ WT^T + ...), WT is [N][K] bf16 ----------
// MODE 0: C=bf16, +bias, optional relu. MODE 1: final (flag picks f32/bf16 out).
// MODE 2: seab: A is f32, C=f32, C = acc*rowscale + (deg>0 ? bias : 0).
template <int K, int N, int ACT, int MODE>
__global__ __launch_bounds__(256) void gemm_kernel(
    const void* __restrict__ Av, const u16* __restrict__ WT,
    const float* __restrict__ bias, void* __restrict__ Cv, int M,
    const int* __restrict__ flag, const float* __restrict__ rowscale,
    const int* __restrict__ degp) {
  constexpr int KC = 64;
  constexpr int KCP = KC + 8;        // 144B rows: 16B-aligned, 2-way bank pattern (free)
  constexpr int NF = N / 16;
  constexpr int NV = N * KC / 8;     // 8-elem vectors per K-chunk
  static_assert(K % KC == 0 && N % 16 == 0, "dims");
  __shared__ u16 WS[N * KCP];

  int tid = threadIdx.x, lane = tid & 63, wid = tid >> 6;
  int row0 = blockIdx.x * 64 + wid * 16;
  int arow = row0 + (lane & 15);
  if (arow >= M) arow = M - 1;       // clamp loads; stores guarded

  f32x4 acc[NF];
  #pragma unroll
  for (int i = 0; i < NF; ++i) acc[i] = (f32x4){0.f, 0.f, 0.f, 0.f};

  for (int kc0 = 0; kc0 < K; kc0 += KC) {
    #pragma unroll
    for (int v = tid; v < NV; v += 256) {
      int n = v >> 3, k8 = (v & 7) << 3;
      *reinterpret_cast<short8*>(&WS[n * KCP + k8]) =
          *reinterpret_cast<const short8*>(&WT[(size_t)n * K + kc0 + k8]);
    }
    __syncthreads();
    #pragma unroll
    for (int ks = 0; ks < KC; ks += 32) {
      short8 a;
      if (MODE == 2) {
        const float* Af = (const float*)Av + (size_t)arow * K + kc0 + ((lane >> 4) * 8) + ks;
        f32x4 a0 = *reinterpret_cast<const f32x4*>(Af);
        f32x4 a1 = *reinterpret_cast<const f32x4*>(Af + 4);
        #pragma unroll
        for (int q = 0; q < 4; ++q) { a[q] = (short)f2b(a0[q]); a[q + 4] = (short)f2b(a1[q]); }
      } else {
        const u16* Ab = (const u16*)Av + (size_t)arow * K + kc0 + ((lane >> 4) * 8) + ks;
        a = *reinterpret_cast<const short8*>(Ab);
      }
      #pragma unroll
      for (int nf = 0; nf < NF; ++nf) {
        const u16* bp = &WS[(nf * 16 + (lane & 15)) * KCP + ks + ((lane >> 4) * 8)];
        short8 b = *reinterpret_cast<const short8*>(bp);
        acc[nf] = __builtin_amdgcn_mfma_f32_16x16x32_bf16(a, b, acc[nf], 0, 0, 0);
      }
    }
    __syncthreads();
  }

  int isbf = 1;
  if (MODE == 1) isbf = *flag;
  int crow0 = row0 + ((lane >> 4) * 4);
  #pragma unroll
  for (int nf = 0; nf < NF; ++nf) {
    int col = nf * 16 + (lane & 15);
    float bv = bias[col];
    #pragma unroll
    for (int r = 0; r < 4; ++r) {
      int crow = crow0 + r;
      if (crow < M) {
        size_t idx = (size_t)crow * N + col;
        if (MODE == 2) {
          float v = acc[nf][r] * rowscale[crow] + (degp[crow] > 0 ? bv : 0.f);
          ((float*)Cv)[idx] = v;
        } else {
          float v = acc[nf][r] + bv;
          if (ACT) v = fmaxf(v, 0.f);
          if (MODE == 1 && !isbf) ((float*)Cv)[idx] = v;
          else                    ((u16*)Cv)[idx]   = f2b(v);
        }
      }
    }
  }
}

// ---------- per-layer: h0 = (1+eps)*x + segsum(x[src])*inv_deg + seab ----------
// one wave per node; lane covers 2 of 128 dims; x4 unrolled independent loads
__global__ __launch_bounds__(256) void agg_kernel(
    const u16* __restrict__ xcur, const int* __restrict__ rowptr,
    const int* __restrict__ csr_src, const float* __restrict__ invdeg,
    const float* __restrict__ seab, const float* __restrict__ epsf, int l,
    u16* __restrict__ h0, int nnodes) {
  int tid = threadIdx.x, lane = tid & 63, wid = tid >> 6;
  int node = blockIdx.x * 4 + wid;
  if (node >= nnodes) return;
  const u32* xc = (const u32*)xcur;
  int r0 = rowptr[node], r1 = rowptr[node + 1];
  float p0 = 0.f, p1 = 0.f, q0 = 0.f, q1 = 0.f, s0 = 0.f, s1 = 0.f, t0 = 0.f, t1 = 0.f;
  int j = r0;
  for (; j + 4 <= r1; j += 4) {
    int sa = csr_src[j], sb = csr_src[j + 1], sc = csr_src[j + 2], sd = csr_src[j + 3];
    u32 va = xc[(size_t)sa * 64 + lane];
    u32 vb = xc[(size_t)sb * 64 + lane];
    u32 vc = xc[(size_t)sc * 64 + lane];
    u32 vd = xc[(size_t)sd * 64 + lane];
    p0 += b2f((u16)(va & 0xffff)); p1 += b2f((u16)(va >> 16));
    q0 += b2f((u16)(vb & 0xffff)); q1 += b2f((u16)(vb >> 16));
    s0 += b2f((u16)(vc & 0xffff)); s1 += b2f((u16)(vc >> 16));
    t0 += b2f((u16)(vd & 0xffff)); t1 += b2f((u16)(vd >> 16));
  }
  for (; j < r1; ++j) {
    int s = csr_src[j];
    u32 v = xc[(size_t)s * 64 + lane];
    p0 += b2f((u16)(v & 0xffff)); p1 += b2f((u16)(v >> 16));
  }
  float a0 = (p0 + q0) + (s0 + t0);
  float a1 = (p1 + q1) + (s1 + t1);
  float epl = 1.0f + epsf[l];
  float iv = invdeg[node];
  u32 xv = xc[(size_t)node * 64 + lane];
  float h0v = epl * b2f((u16)(xv & 0xffff)) + a0 * iv + seab[(size_t)node * 128 + lane * 2];
  float h1v = epl * b2f((u16)(xv >> 16))    + a1 * iv + seab[(size_t)node * 128 + lane * 2 + 1];
  u32 packed = (u32)f2b(h0v) | ((u32)f2b(h1v) << 16);
  *reinterpret_cast<u32*>(&h0[(size_t)node * 128 + lane * 2]) = packed;
}

// ---------- launch ----------
extern "C" void kernel_launch(void* const* d_in, const int* in_sizes, int n_in,
                              void* d_out, int out_size, void* d_ws, size_t ws_size,
                              hipStream_t stream) {
  const void* x_in  = d_in[0];
  const void* eattr = d_in[1];
  const int*  eidx  = (const int*)d_in[2];
  const void* nodeW = d_in[3];
  const void* nodeb = d_in[4];
  const void* edgeW = d_in[5];
  const void* edgeb = d_in[6];
  const void* W1    = d_in[7];
  const void* b1    = d_in[8];
  const void* W2    = d_in[9];
  const void* b2    = d_in[10];
  const void* eps   = d_in[11];
  const void* linW  = d_in[12];
  const void* linb  = d_in[13];

  int nn = in_sizes[0] / 128;   // 50000 nodes
  int ne = in_sizes[2] / 2;     // 625000 edges

  char* ws = (char*)d_ws;
  size_t off = 0;
  auto alloc = [&](size_t b) { size_t r = off; off += (b + 255) & ~(size_t)255; return r; };
  int*    flag    = (int*)(ws + alloc(4));
  int*    deg     = (int*)(ws + alloc((size_t)nn * 4));
  int*    fillc   = (int*)(ws + alloc((size_t)nn * 4));
  int*    rowptr  = (int*)(ws + alloc((size_t)(nn + 1) * 4));
  float*  invdeg  = (float*)(ws + alloc((size_t)nn * 4));
  int*    btot    = (int*)(ws + alloc(256 * 4));
  int*    csr_src = (int*)(ws + alloc((size_t)ne * 4));
  float*  sattr   = (float*)(ws + alloc((size_t)nn * 64 * 4));
  float*  seab    = (float*)(ws + alloc((size_t)nn * 128 * 4));
  u16*    xb      = (u16*)(ws + alloc((size_t)nn * 128 * 2));
  u16*    xcur    = (u16*)(ws + alloc((size_t)nn * 128 * 2));
  u16*    h0      = (u16*)(ws + alloc((size_t)nn * 128 * 2));
  u16*    tbuf    = (u16*)(ws + alloc((size_t)nn * 256 * 2));
  u16*    nodeWT  = (u16*)(ws + alloc(128 * 128 * 2));
  u16*    edgeWT  = (u16*)(ws + alloc(64 * 128 * 2));
  u16*    W1T     = (u16*)(ws + alloc((size_t)3 * 128 * 256 * 2));
  u16*    W2T     = (u16*)(ws + alloc((size_t)3 * 256 * 128 * 2));
  u16*    linWT   = (u16*)(ws + alloc(128 * 112 * 2));
  float*  nodebf  = (float*)(ws + alloc(128 * 4));
  float*  edgebf  = (float*)(ws + alloc(128 * 4));
  float*  b1f     = (float*)(ws + alloc(3 * 256 * 4));
  float*  b2f_    = (float*)(ws + alloc(3 * 128 * 4));
  float*  epsf    = (float*)(ws + alloc(3 * 4));
  float*  linbf   = (float*)(ws + alloc(112 * 4));

  hipMemsetAsync(deg, 0, (size_t)nn * 4, stream);
  hipMemsetAsync(fillc, 0, (size_t)nn * 4, stream);
  hipMemsetAsync(sattr, 0, (size_t)nn * 64 * 4, stream);

  sniff_kernel<<<1, 256, 0, stream>>>((const u16*)x_in, flag);

  cvt_bf16_kernel<<<(nn * 128 + 255) / 256, 256, 0, stream>>>(x_in, xb, nn * 128, flag);
  auto tcv = [&](const void* s, u16* d, int K, int N, int L) {
    int tot = L * K * N;
    transpose_cvt_kernel<<<(tot + 255) / 256, 256, 0, stream>>>(s, d, K, N, tot, flag);
  };
  tcv(nodeW, nodeWT, 128, 128, 1);
  tcv(edgeW, edgeWT, 64, 128, 1);
  tcv(W1, W1T, 128, 256, 3);
  tcv(W2, W2T, 256, 128, 3);
  tcv(linW, linWT, 128, 112, 1);

  BiasJobs bj;
  bj.src[0] = nodeb; bj.dst[0] = nodebf; bj.len[0] = 128;
  bj.src[1] = edgeb; bj.dst[1] = edgebf; bj.len[1] = 128;
  bj.src[2] = b1;    bj.dst[2] = b1f;    bj.len[2] = 3 * 256;
  bj.src[3] = b2;    bj.dst[3] = b2f_;   bj.len[3] = 3 * 128;
  bj.src[4] = eps;   bj.dst[4] = epsf;   bj.len[4] = 3;
  bj.src[5] = linb;  bj.dst[5] = linbf;  bj.len[5] = 112;
  cvt_bias_kernel<<<6, 256, 0, stream>>>(bj, flag);

  int eb = (ne + 255) / 256;
  int nb = (nn + 255) / 256;
  deg_kernel<<<eb, 256, 0, stream>>>(eidx + ne, deg, ne);
  scanA_kernel<<<nb, 256, 0, stream>>>(deg, rowptr, invdeg, btot, nn);
  scanB_kernel<<<1, 256, 0, stream>>>(btot, nb);
  scanC_kernel<<<nb, 256, 0, stream>>>(rowptr, btot, nn, ne);
  fill_kernel<<<eb, 256, 0, stream>>>(eidx, eidx + ne, rowptr, fillc, csr_src, ne);

  scatter_kernel<<<(ne + 3) / 4, 256, 0, stream>>>(eattr, eidx + ne, sattr, ne, flag);

  int gb = (nn + 63) / 64;
  gemm_kernel<128, 128, 0, 0><<<gb, 256, 0, stream>>>(xb, nodeWT, nodebf, xcur, nn, flag, nullptr, nullptr);
  gemm_kernel<64, 128, 0, 2><<<gb, 256, 0, stream>>>(sattr, edgeWT, edgebf, seab, nn, flag, invdeg, deg);

  for (int l = 0; l < 3; ++l) {
    agg_kernel<<<(nn + 3) / 4, 256, 0, stream>>>(xcur, rowptr, csr_src, invdeg, seab, epsf, l, h0, nn);
    gemm_kernel<128, 256, 1, 0><<<gb, 256, 0, stream>>>(h0, W1T + (size_t)l * 128 * 256,
                                                        b1f + l * 256, tbuf, nn, flag, nullptr, nullptr);
    gemm_kernel<256, 128, 1, 0><<<gb, 256, 0, stream>>>(tbuf, W2T + (size_t)l * 256 * 128,
                                                        b2f_ + l * 128, xcur, nn, flag, nullptr, nullptr);
  }
  gemm_kernel<128, 112, 0, 1><<<gb, 256, 0, stream>>>(xcur, linWT, linbf, d_out, nn, flag, nullptr, nullptr);
}

// Round 5
// 719.002 us; speedup vs baseline: 1.2069x; 1.0343x over previous
//
#include <hip/hip_runtime.h>

// GIN on MI355X. Algebra: segsum(x[src]+ea) = segsum(x[src]) + segsum(ea), and
// segsum(edge_attr@We + be) = segsum(edge_attr)@We + deg*be.
// => edge features read ONCE via atomic-free half-wave CSR gather into sattr[N,64] f32;
//    per-layer work = CSR gather of x + 2 MFMA GEMMs (32 rows/wave, 128-row blocks).

typedef unsigned short u16;
typedef unsigned int   u32;

using short8 = __attribute__((ext_vector_type(8))) short;
using f32x4  = __attribute__((ext_vector_type(4))) float;
using f32x2  = __attribute__((ext_vector_type(2))) float;

__device__ __forceinline__ float b2f(u16 u) {
  union { u32 i; float f; } v; v.i = ((u32)u) << 16; return v.f;
}
__device__ __forceinline__ u16 f2b(float f) {
  union { float f; u32 i; } v; v.f = f;
  u32 i = v.i;
  return (u16)((i + 0x7FFFu + ((i >> 16) & 1u)) >> 16); // RNE
}

// ---------- dtype sniff ----------
__global__ void sniff_kernel(const u16* __restrict__ xu, int* __restrict__ flag) {
  __shared__ int cnt;
  if (threadIdx.x == 0) cnt = 0;
  __syncthreads();
  int c = 0;
  for (int i = threadIdx.x; i < 1024; i += 256) {
    int e = (xu[i] >> 7) & 0xFF;
    if (e >= 100 && e <= 140) c++;
  }
  atomicAdd(&cnt, c);
  __syncthreads();
  if (threadIdx.x == 0) *flag = (cnt >= 820) ? 1 : 0;   // 1 = bf16 layout
}

__global__ void cvt_bf16_kernel(const void* __restrict__ src, u16* __restrict__ dst,
                                int n, const int* __restrict__ flag) {
  int i = blockIdx.x * 256 + threadIdx.x;
  if (i >= n) return;
  if (*flag) dst[i] = ((const u16*)src)[i];
  else       dst[i] = f2b(((const float*)src)[i]);
}

// transpose+cvt: src [L][K][N] -> dst [L][N][K] (bf16)
__global__ void transpose_cvt_kernel(const void* __restrict__ src, u16* __restrict__ dst,
                                     int K, int N, int total, const int* __restrict__ flag) {
  int i = blockIdx.x * 256 + threadIdx.x;
  if (i >= total) return;
  int kn = K * N;
  int l = i / kn, r = i - l * kn;
  int k = r / N, n = r - k * N;
  u16 v = (*flag) ? ((const u16*)src)[i] : f2b(((const float*)src)[i]);
  dst[(size_t)l * kn + n * K + k] = v;
}

struct BiasJobs { const void* src[6]; float* dst[6]; int len[6]; };
__global__ void cvt_bias_kernel(BiasJobs j, const int* __restrict__ flag) {
  int b = blockIdx.x;
  int isbf = *flag;
  for (int i = threadIdx.x; i < j.len[b]; i += 256) {
    j.dst[b][i] = isbf ? b2f(((const u16*)j.src[b])[i]) : ((const float*)j.src[b])[i];
  }
}

// ---------- CSR build ----------
__global__ void deg_kernel(const int* __restrict__ dst, int* __restrict__ deg, int e) {
  int i = blockIdx.x * 256 + threadIdx.x;
  if (i < e) atomicAdd(&deg[dst[i]], 1);
}

__global__ void scanA_kernel(const int* __restrict__ deg, int* __restrict__ rowptr,
                             float* __restrict__ invdeg, int* __restrict__ btot, int n) {
  __shared__ int wsum[4];
  int tid = threadIdx.x, lane = tid & 63, wid = tid >> 6;
  int i = blockIdx.x * 256 + tid;
  int v = (i < n) ? deg[i] : 0;
  int incl = v;
  #pragma unroll
  for (int off = 1; off < 64; off <<= 1) {
    int t = __shfl_up(incl, off, 64);
    if (lane >= off) incl += t;
  }
  if (lane == 63) wsum[wid] = incl;
  __syncthreads();
  int woff = 0;
  for (int w = 0; w < wid; ++w) woff += wsum[w];
  if (i < n) {
    rowptr[i] = woff + incl - v;
    invdeg[i] = 1.0f / fmaxf((float)v, 1.0f);
  }
  if (tid == 255) btot[blockIdx.x] = woff + incl;
}

__global__ void scanB_kernel(int* __restrict__ btot, int nb) {
  __shared__ int wsum[4];
  int tid = threadIdx.x, lane = tid & 63, wid = tid >> 6;
  int v = (tid < nb) ? btot[tid] : 0;
  int incl = v;
  #pragma unroll
  for (int off = 1; off < 64; off <<= 1) {
    int t = __shfl_up(incl, off, 64);
    if (lane >= off) incl += t;
  }
  if (lane == 63) wsum[wid] = incl;
  __syncthreads();
  int woff = 0;
  for (int w = 0; w < wid; ++w) woff += wsum[w];
  if (tid < nb) btot[tid] = woff + incl - v;
}

__global__ void scanC_kernel(int* __restrict__ rowptr, const int* __restrict__ btot,
                             int n, int e) {
  int i = blockIdx.x * 256 + threadIdx.x;
  if (i < n) rowptr[i] += btot[blockIdx.x];
  if (i == 0) rowptr[n] = e;
}

__global__ void fill_kernel(const int* __restrict__ src, const int* __restrict__ dst,
                            const int* __restrict__ rowptr, int* __restrict__ fillc,
                            int* __restrict__ csr_src, int* __restrict__ csr_eid, int e) {
  int i = blockIdx.x * 256 + threadIdx.x;
  if (i < e) {
    int d = dst[i];
    int p = rowptr[d] + atomicAdd(&fillc[d], 1);
    csr_src[p] = src[i];
    csr_eid[p] = i;
  }
}

// ---------- edge gather: sattr[node][0:64] = sum over in-edges of edge_attr, no atomics ----
// wave per node; half-wave (32 lanes x u32) covers one 128B bf16 edge row; 8 edges in flight.
__global__ __launch_bounds__(256) void sattr_gather_kernel(
    const void* __restrict__ ea, const int* __restrict__ rowptr,
    const int* __restrict__ csr_eid, float* __restrict__ sattr,
    int nnodes, const int* __restrict__ flag) {
  int tid = threadIdx.x, lane = tid & 63, wid = tid >> 6;
  int node = blockIdx.x * 4 + wid;
  if (node >= nnodes) return;
  int hl = lane >> 5, l32 = lane & 31;
  int r0 = rowptr[node], r1 = rowptr[node + 1];
  int isbf = *flag;
  float s0 = 0.f, s1 = 0.f;
  if (isbf) {
    const u32* ea32 = (const u32*)ea;   // [E][32] bf16-pairs
    int j = r0 + hl;
    for (; j + 6 < r1; j += 8) {
      int e0 = csr_eid[j], e1 = csr_eid[j + 2], e2 = csr_eid[j + 4], e3 = csr_eid[j + 6];
      u32 v0 = ea32[(size_t)e0 * 32 + l32];
      u32 v1 = ea32[(size_t)e1 * 32 + l32];
      u32 v2 = ea32[(size_t)e2 * 32 + l32];
      u32 v3 = ea32[(size_t)e3 * 32 + l32];
      s0 += b2f((u16)(v0 & 0xffff)) + b2f((u16)(v1 & 0xffff)) +
            b2f((u16)(v2 & 0xffff)) + b2f((u16)(v3 & 0xffff));
      s1 += b2f((u16)(v0 >> 16)) + b2f((u16)(v1 >> 16)) +
            b2f((u16)(v2 >> 16)) + b2f((u16)(v3 >> 16));
    }
    for (; j < r1; j += 2) {
      u32 v = ea32[(size_t)csr_eid[j] * 32 + l32];
      s0 += b2f((u16)(v & 0xffff));
      s1 += b2f((u16)(v >> 16));
    }
  } else {
    const f32x2* eaf = (const f32x2*)ea;  // [E][32] float-pairs
    int j = r0 + hl;
    for (; j + 6 < r1; j += 8) {
      f32x2 v0 = eaf[(size_t)csr_eid[j] * 32 + l32];
      f32x2 v1 = eaf[(size_t)csr_eid[j + 2] * 32 + l32];
      f32x2 v2 = eaf[(size_t)csr_eid[j + 4] * 32 + l32];
      f32x2 v3 = eaf[(size_t)csr_eid[j + 6] * 32 + l32];
      s0 += v0.x + v1.x + v2.x + v3.x;
      s1 += v0.y + v1.y + v2.y + v3.y;
    }
    for (; j < r1; j += 2) {
      f32x2 v = eaf[(size_t)csr_eid[j] * 32 + l32];
      s0 += v.x; s1 += v.y;
    }
  }
  s0 += __shfl_xor(s0, 32, 64);
  s1 += __shfl_xor(s1, 32, 64);
  if (hl == 0) {
    f32x2 o; o.x = s0; o.y = s1;
    *reinterpret_cast<f32x2*>(&sattr[(size_t)node * 64 + l32 * 2]) = o;
  }
}

// ---------- GEMM: C[M,N] = epilogue(A[M,K] @ WT^T + ...), WT is [N][K] bf16 ----------
// 256 thr = 4 waves; 128 rows/block; wave = 32 rows (2x16 rowblocks sharing B-frags).
// MODE 0: C=bf16, +bias, optional relu. MODE 1: final (flag picks f32/bf16 out).
// MODE 2: seab: A is f32, C=f32, C = acc*rowscale + (deg>0 ? bias : 0).
template <int K, int N, int ACT, int MODE>
__global__ __launch_bounds__(256) void gemm_kernel(
    const void* __restrict__ Av, const u16* __restrict__ WT,
    const float* __restrict__ bias, void* __restrict__ Cv, int M,
    const int* __restrict__ flag, const float* __restrict__ rowscale,
    const int* __restrict__ degp) {
  constexpr int KC = 64;
  constexpr int KCP = KC + 8;        // 144B rows: 16B-aligned
  constexpr int NF = N / 16;
  constexpr int NV = N * KC / 8;
  static_assert(K % KC == 0 && N % 16 == 0, "dims");
  __shared__ u16 WS[N * KCP];

  int tid = threadIdx.x, lane = tid & 63, wid = tid >> 6;
  int lane16 = lane & 15, lh = lane >> 4;
  int row0 = blockIdx.x * 128 + wid * 32;
  int arow0 = row0 + lane16;       if (arow0 >= M) arow0 = M - 1;
  int arow1 = row0 + 16 + lane16;  if (arow1 >= M) arow1 = M - 1;

  f32x4 acc[2][NF];
  #pragma unroll
  for (int rb = 0; rb < 2; ++rb)
    #pragma unroll
    for (int i = 0; i < NF; ++i) acc[rb][i] = (f32x4){0.f, 0.f, 0.f, 0.f};

  for (int kc0 = 0; kc0 < K; kc0 += KC) {
    #pragma unroll
    for (int v = tid; v < NV; v += 256) {
      int n = v >> 3, k8 = (v & 7) << 3;
      *reinterpret_cast<short8*>(&WS[n * KCP + k8]) =
          *reinterpret_cast<const short8*>(&WT[(size_t)n * K + kc0 + k8]);
    }
    __syncthreads();
    #pragma unroll
    for (int ks = 0; ks < KC; ks += 32) {
      short8 a0, a1;
      if (MODE == 2) {
        const float* Af0 = (const float*)Av + (size_t)arow0 * K + kc0 + ks + lh * 8;
        const float* Af1 = (const float*)Av + (size_t)arow1 * K + kc0 + ks + lh * 8;
        f32x4 p0 = *reinterpret_cast<const f32x4*>(Af0);
        f32x4 p1 = *reinterpret_cast<const f32x4*>(Af0 + 4);
        f32x4 q0 = *reinterpret_cast<const f32x4*>(Af1);
        f32x4 q1 = *reinterpret_cast<const f32x4*>(Af1 + 4);
        #pragma unroll
        for (int q = 0; q < 4; ++q) {
          a0[q] = (short)f2b(p0[q]); a0[q + 4] = (short)f2b(p1[q]);
          a1[q] = (short)f2b(q0[q]); a1[q + 4] = (short)f2b(q1[q]);
        }
      } else {
        a0 = *reinterpret_cast<const short8*>((const u16*)Av + (size_t)arow0 * K + kc0 + ks + lh * 8);
        a1 = *reinterpret_cast<const short8*>((const u16*)Av + (size_t)arow1 * K + kc0 + ks + lh * 8);
      }
      #pragma unroll
      for (int nf = 0; nf < NF; ++nf) {
        short8 b = *reinterpret_cast<const short8*>(&WS[(nf * 16 + lane16) * KCP + ks + lh * 8]);
        acc[0][nf] = __builtin_amdgcn_mfma_f32_16x16x32_bf16(a0, b, acc[0][nf], 0, 0, 0);
        acc[1][nf] = __builtin_amdgcn_mfma_f32_16x16x32_bf16(a1, b, acc[1][nf], 0, 0, 0);
      }
    }
    __syncthreads();
  }

  int isbf = 1;
  if (MODE == 1) isbf = *flag;
  #pragma unroll
  for (int rb = 0; rb < 2; ++rb) {
    int crow0 = row0 + rb * 16 + lh * 4;
    #pragma unroll
    for (int nf = 0; nf < NF; ++nf) {
      int col = nf * 16 + lane16;
      float bv = bias[col];
      #pragma unroll
      for (int r = 0; r < 4; ++r) {
        int crow = crow0 + r;
        if (crow < M) {
          size_t idx = (size_t)crow * N + col;
          if (MODE == 2) {
            ((float*)Cv)[idx] = acc[rb][nf][r] * rowscale[crow] + (degp[crow] > 0 ? bv : 0.f);
          } else {
            float v = acc[rb][nf][r] + bv;
            if (ACT) v = fmaxf(v, 0.f);
            if (MODE == 1 && !isbf) ((float*)Cv)[idx] = v;
            else                    ((u16*)Cv)[idx]   = f2b(v);
          }
        }
      }
    }
  }
}

// ---------- per-layer: h0 = (1+eps)*x + segsum(x[src])*inv_deg + seab ----------
// one wave per node; lane covers 2 of 128 dims; x8 independent loads in flight
__global__ __launch_bounds__(256) void agg_kernel(
    const u16* __restrict__ xcur, const int* __restrict__ rowptr,
    const int* __restrict__ csr_src, const float* __restrict__ invdeg,
    const float* __restrict__ seab, const float* __restrict__ epsf, int l,
    u16* __restrict__ h0, int nnodes) {
  int tid = threadIdx.x, lane = tid & 63, wid = tid >> 6;
  int node = blockIdx.x * 4 + wid;
  if (node >= nnodes) return;
  const u32* xc = (const u32*)xcur;
  int r0 = rowptr[node], r1 = rowptr[node + 1];
  float a0 = 0.f, a1 = 0.f;
  int j = r0;
  for (; j + 8 <= r1; j += 8) {
    int s0 = csr_src[j],     s1 = csr_src[j + 1], s2 = csr_src[j + 2], s3 = csr_src[j + 3];
    int s4 = csr_src[j + 4], s5 = csr_src[j + 5], s6 = csr_src[j + 6], s7 = csr_src[j + 7];
    u32 v0 = xc[(size_t)s0 * 64 + lane];
    u32 v1 = xc[(size_t)s1 * 64 + lane];
    u32 v2 = xc[(size_t)s2 * 64 + lane];
    u32 v3 = xc[(size_t)s3 * 64 + lane];
    u32 v4 = xc[(size_t)s4 * 64 + lane];
    u32 v5 = xc[(size_t)s5 * 64 + lane];
    u32 v6 = xc[(size_t)s6 * 64 + lane];
    u32 v7 = xc[(size_t)s7 * 64 + lane];
    a0 += ((b2f((u16)(v0 & 0xffff)) + b2f((u16)(v1 & 0xffff))) +
           (b2f((u16)(v2 & 0xffff)) + b2f((u16)(v3 & 0xffff)))) +
          ((b2f((u16)(v4 & 0xffff)) + b2f((u16)(v5 & 0xffff))) +
           (b2f((u16)(v6 & 0xffff)) + b2f((u16)(v7 & 0xffff))));
    a1 += ((b2f((u16)(v0 >> 16)) + b2f((u16)(v1 >> 16))) +
           (b2f((u16)(v2 >> 16)) + b2f((u16)(v3 >> 16)))) +
          ((b2f((u16)(v4 >> 16)) + b2f((u16)(v5 >> 16))) +
           (b2f((u16)(v6 >> 16)) + b2f((u16)(v7 >> 16))));
  }
  for (; j < r1; ++j) {
    u32 v = xc[(size_t)csr_src[j] * 64 + lane];
    a0 += b2f((u16)(v & 0xffff));
    a1 += b2f((u16)(v >> 16));
  }
  float epl = 1.0f + epsf[l];
  float iv = invdeg[node];
  u32 xv = xc[(size_t)node * 64 + lane];
  float h0v = epl * b2f((u16)(xv & 0xffff)) + a0 * iv + seab[(size_t)node * 128 + lane * 2];
  float h1v = epl * b2f((u16)(xv >> 16))    + a1 * iv + seab[(size_t)node * 128 + lane * 2 + 1];
  u32 packed = (u32)f2b(h0v) | ((u32)f2b(h1v) << 16);
  *reinterpret_cast<u32*>(&h0[(size_t)node * 128 + lane * 2]) = packed;
}

// ---------- launch ----------
extern "C" void kernel_launch(void* const* d_in, const int* in_sizes, int n_in,
                              void* d_out, int out_size, void* d_ws, size_t ws_size,
                              hipStream_t stream) {
  const void* x_in  = d_in[0];
  const void* eattr = d_in[1];
  const int*  eidx  = (const int*)d_in[2];
  const void* nodeW = d_in[3];
  const void* nodeb = d_in[4];
  const void* edgeW = d_in[5];
  const void* edgeb = d_in[6];
  const void* W1    = d_in[7];
  const void* b1    = d_in[8];
  const void* W2    = d_in[9];
  const void* b2    = d_in[10];
  const void* eps   = d_in[11];
  const void* linW  = d_in[12];
  const void* linb  = d_in[13];

  int nn = in_sizes[0] / 128;   // 50000 nodes
  int ne = in_sizes[2] / 2;     // 625000 edges

  char* ws = (char*)d_ws;
  size_t off = 0;
  auto alloc = [&](size_t b) { size_t r = off; off += (b + 255) & ~(size_t)255; return r; };
  int*    flag    = (int*)(ws + alloc(4));
  int*    deg     = (int*)(ws + alloc((size_t)nn * 4));
  int*    fillc   = (int*)(ws + alloc((size_t)nn * 4));
  int*    rowptr  = (int*)(ws + alloc((size_t)(nn + 1) * 4));
  float*  invdeg  = (float*)(ws + alloc((size_t)nn * 4));
  int*    btot    = (int*)(ws + alloc(256 * 4));
  int*    csr_src = (int*)(ws + alloc((size_t)ne * 4));
  int*    csr_eid = (int*)(ws + alloc((size_t)ne * 4));
  float*  sattr   = (float*)(ws + alloc((size_t)nn * 64 * 4));
  float*  seab    = (float*)(ws + alloc((size_t)nn * 128 * 4));
  u16*    xb      = (u16*)(ws + alloc((size_t)nn * 128 * 2));
  u16*    xcur    = (u16*)(ws + alloc((size_t)nn * 128 * 2));
  u16*    h0      = (u16*)(ws + alloc((size_t)nn * 128 * 2));
  u16*    tbuf    = (u16*)(ws + alloc((size_t)nn * 256 * 2));
  u16*    nodeWT  = (u16*)(ws + alloc(128 * 128 * 2));
  u16*    edgeWT  = (u16*)(ws + alloc(64 * 128 * 2));
  u16*    W1T     = (u16*)(ws + alloc((size_t)3 * 128 * 256 * 2));
  u16*    W2T     = (u16*)(ws + alloc((size_t)3 * 256 * 128 * 2));
  u16*    linWT   = (u16*)(ws + alloc(128 * 112 * 2));
  float*  nodebf  = (float*)(ws + alloc(128 * 4));
  float*  edgebf  = (float*)(ws + alloc(128 * 4));
  float*  b1f     = (float*)(ws + alloc(3 * 256 * 4));
  float*  b2f_    = (float*)(ws + alloc(3 * 128 * 4));
  float*  epsf    = (float*)(ws + alloc(3 * 4));
  float*  linbf   = (float*)(ws + alloc(112 * 4));

  hipMemsetAsync(deg, 0, (size_t)nn * 4, stream);
  hipMemsetAsync(fillc, 0, (size_t)nn * 4, stream);

  sniff_kernel<<<1, 256, 0, stream>>>((const u16*)x_in, flag);

  cvt_bf16_kernel<<<(nn * 128 + 255) / 256, 256, 0, stream>>>(x_in, xb, nn * 128, flag);
  auto tcv = [&](const void* s, u16* d, int K, int N, int L) {
    int tot = L * K * N;
    transpose_cvt_kernel<<<(tot + 255) / 256, 256, 0, stream>>>(s, d, K, N, tot, flag);
  };
  tcv(nodeW, nodeWT, 128, 128, 1);
  tcv(edgeW, edgeWT, 64, 128, 1);
  tcv(W1, W1T, 128, 256, 3);
  tcv(W2, W2T, 256, 128, 3);
  tcv(linW, linWT, 128, 112, 1);

  BiasJobs bj;
  bj.src[0] = nodeb; bj.dst[0] = nodebf; bj.len[0] = 128;
  bj.src[1] = edgeb; bj.dst[1] = edgebf; bj.len[1] = 128;
  bj.src[2] = b1;    bj.dst[2] = b1f;    bj.len[2] = 3 * 256;
  bj.src[3] = b2;    bj.dst[3] = b2f_;   bj.len[3] = 3 * 128;
  bj.src[4] = eps;   bj.dst[4] = epsf;   bj.len[4] = 3;
  bj.src[5] = linb;  bj.dst[5] = linbf;  bj.len[5] = 112;
  cvt_bias_kernel<<<6, 256, 0, stream>>>(bj, flag);

  int eb = (ne + 255) / 256;
  int nb = (nn + 255) / 256;
  deg_kernel<<<eb, 256, 0, stream>>>(eidx + ne, deg, ne);
  scanA_kernel<<<nb, 256, 0, stream>>>(deg, rowptr, invdeg, btot, nn);
  scanB_kernel<<<1, 256, 0, stream>>>(btot, nb);
  scanC_kernel<<<nb, 256, 0, stream>>>(rowptr, btot, nn, ne);
  fill_kernel<<<eb, 256, 0, stream>>>(eidx, eidx + ne, rowptr, fillc, csr_src, csr_eid, ne);

  sattr_gather_kernel<<<(nn + 3) / 4, 256, 0, stream>>>(eattr, rowptr, csr_eid, sattr, nn, flag);

  int gb = (nn + 127) / 128;
  gemm_kernel<128, 128, 0, 0><<<gb, 256, 0, stream>>>(xb, nodeWT, nodebf, xcur, nn, flag, nullptr, nullptr);
  gemm_kernel<64, 128, 0, 2><<<gb, 256, 0, stream>>>(sattr, edgeWT, edgebf, seab, nn, flag, invdeg, deg);

  for (int l = 0; l < 3; ++l) {
    agg_kernel<<<(nn + 3) / 4, 256, 0, stream>>>(xcur, rowptr, csr_src, invdeg, seab, epsf, l, h0, nn);
    gemm_kernel<128, 256, 1, 0><<<gb, 256, 0, stream>>>(h0, W1T + (size_t)l * 128 * 256,
                                                        b1f + l * 256, tbuf, nn, flag, nullptr, nullptr);
    gemm_kernel<256, 128, 1, 0><<<gb, 256, 0, stream>>>(tbuf, W2T + (size_t)l * 256 * 128,
                                                        b2f_ + l * 128, xcur, nn, flag, nullptr, nullptr);
  }
  gemm_kernel<128, 112, 0, 1><<<gb, 256, 0, stream>>>(xcur, linWT, linbf, d_out, nn, flag, nullptr, nullptr);
}

// Round 6
// 718.515 us; speedup vs baseline: 1.2077x; 1.0007x over previous
//
#include <hip/hip_runtime.h>

// GIN on MI355X. Algebra: segsum(x[src]+ea) = segsum(x[src]) + segsum(ea), and
// segsum(edge_attr@We + be) = segsum(edge_attr)@We + deg*be.
// => edge features read ONCE via atomic-free half-wave CSR gather into sattr[N,64] f32;
//    per-layer work = CSR gather of x + 2 MFMA GEMMs (32 rows/wave, 64-row 2-wave blocks).

typedef unsigned short u16;
typedef unsigned int   u32;

using short8 = __attribute__((ext_vector_type(8))) short;
using f32x4  = __attribute__((ext_vector_type(4))) float;
using f32x2  = __attribute__((ext_vector_type(2))) float;

__device__ __forceinline__ float b2f(u16 u) {
  union { u32 i; float f; } v; v.i = ((u32)u) << 16; return v.f;
}
__device__ __forceinline__ u16 f2b(float f) {
  union { float f; u32 i; } v; v.f = f;
  u32 i = v.i;
  return (u16)((i + 0x7FFFu + ((i >> 16) & 1u)) >> 16); // RNE
}

// ---------- dtype sniff ----------
__global__ void sniff_kernel(const u16* __restrict__ xu, int* __restrict__ flag) {
  __shared__ int cnt;
  if (threadIdx.x == 0) cnt = 0;
  __syncthreads();
  int c = 0;
  for (int i = threadIdx.x; i < 1024; i += 256) {
    int e = (xu[i] >> 7) & 0xFF;
    if (e >= 100 && e <= 140) c++;
  }
  atomicAdd(&cnt, c);
  __syncthreads();
  if (threadIdx.x == 0) *flag = (cnt >= 820) ? 1 : 0;   // 1 = bf16 layout
}

// ---------- fused prep: 5 weight transpose+cvt groups, 6 bias cvts ----------
struct PrepJobs {
  const void* wsrc[5]; u16* wdst[5];
  int wK[5], wN[5], wTot[5];
  const void* bsrc[6]; float* bdst[6]; int blen[6];
};
__global__ void prep_kernel(PrepJobs j, const int* __restrict__ flag, int grand) {
  int i = blockIdx.x * 256 + threadIdx.x;
  if (i >= grand) return;
  int isbf = *flag;
  #pragma unroll
  for (int g = 0; g < 5; ++g) {
    if (i < j.wTot[g]) {
      int K = j.wK[g], N = j.wN[g];
      int kn = K * N;
      int l = i / kn, r = i - l * kn;
      int k = r / N, n = r - k * N;
      u16 v = isbf ? ((const u16*)j.wsrc[g])[i] : f2b(((const float*)j.wsrc[g])[i]);
      j.wdst[g][(size_t)l * kn + n * K + k] = v;
      return;
    }
    i -= j.wTot[g];
  }
  #pragma unroll
  for (int g = 0; g < 6; ++g) {
    if (i < j.blen[g]) {
      j.bdst[g][i] = isbf ? b2f(((const u16*)j.bsrc[g])[i]) : ((const float*)j.bsrc[g])[i];
      return;
    }
    i -= j.blen[g];
  }
}

// ---------- CSR build ----------
__global__ void deg_kernel(const int* __restrict__ dst, int* __restrict__ deg, int e) {
  int i = blockIdx.x * 256 + threadIdx.x;
  if (i < e) atomicAdd(&deg[dst[i]], 1);
}

__global__ void scanA_kernel(const int* __restrict__ deg, int* __restrict__ rowptr,
                             float* __restrict__ invdeg, int* __restrict__ btot, int n) {
  __shared__ int wsum[4];
  int tid = threadIdx.x, lane = tid & 63, wid = tid >> 6;
  int i = blockIdx.x * 256 + tid;
  int v = (i < n) ? deg[i] : 0;
  int incl = v;
  #pragma unroll
  for (int off = 1; off < 64; off <<= 1) {
    int t = __shfl_up(incl, off, 64);
    if (lane >= off) incl += t;
  }
  if (lane == 63) wsum[wid] = incl;
  __syncthreads();
  int woff = 0;
  for (int w = 0; w < wid; ++w) woff += wsum[w];
  if (i < n) {
    rowptr[i] = woff + incl - v;
    invdeg[i] = 1.0f / fmaxf((float)v, 1.0f);
  }
  if (tid == 255) btot[blockIdx.x] = woff + incl;
}

// merged scanB+scanC: per block computes prefix of btot[0..bid) then offsets rows
__global__ void scanC_kernel(int* __restrict__ rowptr, const int* __restrict__ btot,
                             int n, int e) {
  __shared__ int wsum[4];
  __shared__ int s_pre;
  int bid = blockIdx.x, tid = threadIdx.x, lane = tid & 63, wid = tid >> 6;
  int v = (tid < bid) ? btot[tid] : 0;   // nb <= 256 assumed (n <= 65536)
  #pragma unroll
  for (int off = 1; off < 64; off <<= 1) v += __shfl_xor(v, off, 64);
  if (lane == 0) wsum[wid] = v;
  __syncthreads();
  if (tid == 0) s_pre = wsum[0] + wsum[1] + wsum[2] + wsum[3];
  __syncthreads();
  int i = bid * 256 + tid;
  if (i < n) rowptr[i] += s_pre;
  if (i == 0) rowptr[n] = e;
}

__global__ void fill_kernel(const int* __restrict__ src, const int* __restrict__ dst,
                            const int* __restrict__ rowptr, int* __restrict__ fillc,
                            int2* __restrict__ csr, int e) {
  int i = blockIdx.x * 256 + threadIdx.x;
  if (i < e) {
    int d = dst[i];
    int p = rowptr[d] + atomicAdd(&fillc[d], 1);
    csr[p] = make_int2(src[i], i);   // {src node, edge id}
  }
}

// ---------- edge gather: sattr[node][0:64] = sum of in-edge rows, no atomics ----------
// wave per node; half-wave (32 lanes x u32) covers one 128B bf16 edge row; 8 rows in flight.
__global__ __launch_bounds__(256) void sattr_gather_kernel(
    const void* __restrict__ ea, const int* __restrict__ rowptr,
    const int2* __restrict__ csr, float* __restrict__ sattr,
    int nnodes, const int* __restrict__ flag) {
  int tid = threadIdx.x, lane = tid & 63, wid = tid >> 6;
  int node = blockIdx.x * 4 + wid;
  if (node >= nnodes) return;
  int hl = lane >> 5, l32 = lane & 31;
  int r0 = rowptr[node], r1 = rowptr[node + 1];
  int isbf = *flag;
  float s0 = 0.f, s1 = 0.f;
  if (isbf) {
    const u32* ea32 = (const u32*)ea;   // [E][32] bf16-pairs
    int j = r0 + hl;
    for (; j + 6 < r1; j += 8) {
      int e0 = csr[j].y, e1 = csr[j + 2].y, e2 = csr[j + 4].y, e3 = csr[j + 6].y;
      u32 v0 = ea32[(size_t)e0 * 32 + l32];
      u32 v1 = ea32[(size_t)e1 * 32 + l32];
      u32 v2 = ea32[(size_t)e2 * 32 + l32];
      u32 v3 = ea32[(size_t)e3 * 32 + l32];
      s0 += b2f((u16)(v0 & 0xffff)) + b2f((u16)(v1 & 0xffff)) +
            b2f((u16)(v2 & 0xffff)) + b2f((u16)(v3 & 0xffff));
      s1 += b2f((u16)(v0 >> 16)) + b2f((u16)(v1 >> 16)) +
            b2f((u16)(v2 >> 16)) + b2f((u16)(v3 >> 16));
    }
    for (; j < r1; j += 2) {
      u32 v = ea32[(size_t)csr[j].y * 32 + l32];
      s0 += b2f((u16)(v & 0xffff));
      s1 += b2f((u16)(v >> 16));
    }
  } else {
    const f32x2* eaf = (const f32x2*)ea;  // [E][32] float-pairs
    int j = r0 + hl;
    for (; j + 6 < r1; j += 8) {
      f32x2 v0 = eaf[(size_t)csr[j].y * 32 + l32];
      f32x2 v1 = eaf[(size_t)csr[j + 2].y * 32 + l32];
      f32x2 v2 = eaf[(size_t)csr[j + 4].y * 32 + l32];
      f32x2 v3 = eaf[(size_t)csr[j + 6].y * 32 + l32];
      s0 += v0.x + v1.x + v2.x + v3.x;
      s1 += v0.y + v1.y + v2.y + v3.y;
    }
    for (; j < r1; j += 2) {
      f32x2 v = eaf[(size_t)csr[j].y * 32 + l32];
      s0 += v.x; s1 += v.y;
    }
  }
  s0 += __shfl_xor(s0, 32, 64);
  s1 += __shfl_xor(s1, 32, 64);
  if (hl == 0) {
    f32x2 o; o.x = s0; o.y = s1;
    *reinterpret_cast<f32x2*>(&sattr[(size_t)node * 64 + l32 * 2]) = o;
  }
}

// ---------- GEMM: C[M,N] = epilogue(A[M,K] @ WT^T + ...), WT is [N][K] bf16 ----------
// 128 thr = 2 waves; 64 rows/block (grid ~782, balanced); wave = 32 rows sharing B-frags.
// MODE 0: bf16 A, bf16 C, +bias, opt relu.  MODE 1: final, flag picks f32/bf16 out.
// MODE 2: f32 A (sattr), f32 C = acc*rowscale + (deg>0 ? bias : 0).
// MODE 3: flag-dtype A (raw x input), bf16 C (fused encoder cvt).
template <int K, int N, int ACT, int MODE>
__global__ __launch_bounds__(128) void gemm_kernel(
    const void* __restrict__ Av, const u16* __restrict__ WT,
    const float* __restrict__ bias, void* __restrict__ Cv, int M,
    const int* __restrict__ flag, const float* __restrict__ rowscale,
    const int* __restrict__ degp) {
  constexpr int KC = 64;
  constexpr int KCP = KC + 8;        // 144B rows: 16B-aligned
  constexpr int NF = N / 16;
  constexpr int NV = N * KC / 8;
  static_assert(K % KC == 0 && N % 16 == 0, "dims");
  __shared__ u16 WS[N * KCP];

  int tid = threadIdx.x, lane = tid & 63, wid = tid >> 6;  // wid 0..1
  int lane16 = lane & 15, lh = lane >> 4;
  int row0 = blockIdx.x * 64 + wid * 32;
  int arow0 = row0 + lane16;       if (arow0 >= M) arow0 = M - 1;
  int arow1 = row0 + 16 + lane16;  if (arow1 >= M) arow1 = M - 1;

  int aisbf = 1;
  if (MODE == 3 || MODE == 1) aisbf = *flag;

  f32x4 acc[2][NF];
  #pragma unroll
  for (int rb = 0; rb < 2; ++rb)
    #pragma unroll
    for (int i = 0; i < NF; ++i) acc[rb][i] = (f32x4){0.f, 0.f, 0.f, 0.f};

  for (int kc0 = 0; kc0 < K; kc0 += KC) {
    #pragma unroll
    for (int v = tid; v < NV; v += 128) {
      int n = v >> 3, k8 = (v & 7) << 3;
      *reinterpret_cast<short8*>(&WS[n * KCP + k8]) =
          *reinterpret_cast<const short8*>(&WT[(size_t)n * K + kc0 + k8]);
    }
    __syncthreads();
    #pragma unroll
    for (int ks = 0; ks < KC; ks += 32) {
      short8 a0, a1;
      bool f32a = (MODE == 2) || (MODE == 3 && !aisbf);
      if (f32a) {
        const float* Af0 = (const float*)Av + (size_t)arow0 * K + kc0 + ks + lh * 8;
        const float* Af1 = (const float*)Av + (size_t)arow1 * K + kc0 + ks + lh * 8;
        f32x4 p0 = *reinterpret_cast<const f32x4*>(Af0);
        f32x4 p1 = *reinterpret_cast<const f32x4*>(Af0 + 4);
        f32x4 q0 = *reinterpret_cast<const f32x4*>(Af1);
        f32x4 q1 = *reinterpret_cast<const f32x4*>(Af1 + 4);
        #pragma unroll
        for (int q = 0; q < 4; ++q) {
          a0[q] = (short)f2b(p0[q]); a0[q + 4] = (short)f2b(p1[q]);
          a1[q] = (short)f2b(q0[q]); a1[q + 4] = (short)f2b(q1[q]);
        }
      } else {
        a0 = *reinterpret_cast<const short8*>((const u16*)Av + (size_t)arow0 * K + kc0 + ks + lh * 8);
        a1 = *reinterpret_cast<const short8*>((const u16*)Av + (size_t)arow1 * K + kc0 + ks + lh * 8);
      }
      #pragma unroll
      for (int nf = 0; nf < NF; ++nf) {
        short8 b = *reinterpret_cast<const short8*>(&WS[(nf * 16 + lane16) * KCP + ks + lh * 8]);
        acc[0][nf] = __builtin_amdgcn_mfma_f32_16x16x32_bf16(a0, b, acc[0][nf], 0, 0, 0);
        acc[1][nf] = __builtin_amdgcn_mfma_f32_16x16x32_bf16(a1, b, acc[1][nf], 0, 0, 0);
      }
    }
    __syncthreads();
  }

  #pragma unroll
  for (int rb = 0; rb < 2; ++rb) {
    int crow0 = row0 + rb * 16 + lh * 4;
    #pragma unroll
    for (int nf = 0; nf < NF; ++nf) {
      int col = nf * 16 + lane16;
      float bv = bias[col];
      #pragma unroll
      for (int r = 0; r < 4; ++r) {
        int crow = crow0 + r;
        if (crow < M) {
          size_t idx = (size_t)crow * N + col;
          if (MODE == 2) {
            ((float*)Cv)[idx] = acc[rb][nf][r] * rowscale[crow] + (degp[crow] > 0 ? bv : 0.f);
          } else {
            float v = acc[rb][nf][r] + bv;
            if (ACT) v = fmaxf(v, 0.f);
            if (MODE == 1 && !aisbf) ((float*)Cv)[idx] = v;
            else                     ((u16*)Cv)[idx]   = f2b(v);
          }
        }
      }
    }
  }
}

// ---------- per-layer: h0 = (1+eps)*x + segsum(x[src])*inv_deg + seab ----------
__global__ __launch_bounds__(256) void agg_kernel(
    const u16* __restrict__ xcur, const int* __restrict__ rowptr,
    const int2* __restrict__ csr, const float* __restrict__ invdeg,
    const float* __restrict__ seab, const float* __restrict__ epsf, int l,
    u16* __restrict__ h0, int nnodes) {
  int tid = threadIdx.x, lane = tid & 63, wid = tid >> 6;
  int node = blockIdx.x * 4 + wid;
  if (node >= nnodes) return;
  const u32* xc = (const u32*)xcur;
  int r0 = rowptr[node], r1 = rowptr[node + 1];
  float a0 = 0.f, a1 = 0.f;
  int j = r0;
  for (; j + 8 <= r1; j += 8) {
    int s0 = csr[j].x,     s1 = csr[j + 1].x, s2 = csr[j + 2].x, s3 = csr[j + 3].x;
    int s4 = csr[j + 4].x, s5 = csr[j + 5].x, s6 = csr[j + 6].x, s7 = csr[j + 7].x;
    u32 v0 = xc[(size_t)s0 * 64 + lane];
    u32 v1 = xc[(size_t)s1 * 64 + lane];
    u32 v2 = xc[(size_t)s2 * 64 + lane];
    u32 v3 = xc[(size_t)s3 * 64 + lane];
    u32 v4 = xc[(size_t)s4 * 64 + lane];
    u32 v5 = xc[(size_t)s5 * 64 + lane];
    u32 v6 = xc[(size_t)s6 * 64 + lane];
    u32 v7 = xc[(size_t)s7 * 64 + lane];
    a0 += ((b2f((u16)(v0 & 0xffff)) + b2f((u16)(v1 & 0xffff))) +
           (b2f((u16)(v2 & 0xffff)) + b2f((u16)(v3 & 0xffff)))) +
          ((b2f((u16)(v4 & 0xffff)) + b2f((u16)(v5 & 0xffff))) +
           (b2f((u16)(v6 & 0xffff)) + b2f((u16)(v7 & 0xffff))));
    a1 += ((b2f((u16)(v0 >> 16)) + b2f((u16)(v1 >> 16))) +
           (b2f((u16)(v2 >> 16)) + b2f((u16)(v3 >> 16)))) +
          ((b2f((u16)(v4 >> 16)) + b2f((u16)(v5 >> 16))) +
           (b2f((u16)(v6 >> 16)) + b2f((u16)(v7 >> 16))));
  }
  for (; j < r1; ++j) {
    u32 v = xc[(size_t)csr[j].x * 64 + lane];
    a0 += b2f((u16)(v & 0xffff));
    a1 += b2f((u16)(v >> 16));
  }
  float epl = 1.0f + epsf[l];
  float iv = invdeg[node];
  u32 xv = xc[(size_t)node * 64 + lane];
  float h0v = epl * b2f((u16)(xv & 0xffff)) + a0 * iv + seab[(size_t)node * 128 + lane * 2];
  float h1v = epl * b2f((u16)(xv >> 16))    + a1 * iv + seab[(size_t)node * 128 + lane * 2 + 1];
  u32 packed = (u32)f2b(h0v) | ((u32)f2b(h1v) << 16);
  *reinterpret_cast<u32*>(&h0[(size_t)node * 128 + lane * 2]) = packed;
}

// ---------- launch ----------
extern "C" void kernel_launch(void* const* d_in, const int* in_sizes, int n_in,
                              void* d_out, int out_size, void* d_ws, size_t ws_size,
                              hipStream_t stream) {
  const void* x_in  = d_in[0];
  const void* eattr = d_in[1];
  const int*  eidx  = (const int*)d_in[2];
  const void* nodeW = d_in[3];
  const void* nodeb = d_in[4];
  const void* edgeW = d_in[5];
  const void* edgeb = d_in[6];
  const void* W1    = d_in[7];
  const void* b1    = d_in[8];
  const void* W2    = d_in[9];
  const void* b2    = d_in[10];
  const void* eps   = d_in[11];
  const void* linW  = d_in[12];
  const void* linb  = d_in[13];

  int nn = in_sizes[0] / 128;   // 50000 nodes
  int ne = in_sizes[2] / 2;     // 625000 edges

  char* ws = (char*)d_ws;
  size_t off = 0;
  auto alloc = [&](size_t b) { size_t r = off; off += (b + 255) & ~(size_t)255; return r; };
  int*    flag    = (int*)(ws + alloc(4));
  int*    deg     = (int*)(ws + alloc((size_t)2 * nn * 4));  // deg | fillc contiguous
  int*    fillc   = deg + nn;
  int*    rowptr  = (int*)(ws + alloc((size_t)(nn + 1) * 4));
  float*  invdeg  = (float*)(ws + alloc((size_t)nn * 4));
  int*    btot    = (int*)(ws + alloc(256 * 4));
  int2*   csr     = (int2*)(ws + alloc((size_t)ne * 8));
  float*  sattr   = (float*)(ws + alloc((size_t)nn * 64 * 4));
  float*  seab    = (float*)(ws + alloc((size_t)nn * 128 * 4));
  u16*    xcur    = (u16*)(ws + alloc((size_t)nn * 128 * 2));
  u16*    h0      = (u16*)(ws + alloc((size_t)nn * 128 * 2));
  u16*    tbuf    = (u16*)(ws + alloc((size_t)nn * 256 * 2));
  u16*    nodeWT  = (u16*)(ws + alloc(128 * 128 * 2));
  u16*    edgeWT  = (u16*)(ws + alloc(64 * 128 * 2));
  u16*    W1T     = (u16*)(ws + alloc((size_t)3 * 128 * 256 * 2));
  u16*    W2T     = (u16*)(ws + alloc((size_t)3 * 256 * 128 * 2));
  u16*    linWT   = (u16*)(ws + alloc(128 * 112 * 2));
  float*  nodebf  = (float*)(ws + alloc(128 * 4));
  float*  edgebf  = (float*)(ws + alloc(128 * 4));
  float*  b1f     = (float*)(ws + alloc(3 * 256 * 4));
  float*  b2f_    = (float*)(ws + alloc(3 * 128 * 4));
  float*  epsf    = (float*)(ws + alloc(3 * 4));
  float*  linbf   = (float*)(ws + alloc(112 * 4));

  hipMemsetAsync(deg, 0, (size_t)2 * nn * 4, stream);

  sniff_kernel<<<1, 256, 0, stream>>>((const u16*)x_in, flag);

  PrepJobs pj;
  pj.wsrc[0] = nodeW; pj.wdst[0] = nodeWT; pj.wK[0] = 128; pj.wN[0] = 128; pj.wTot[0] = 128 * 128;
  pj.wsrc[1] = edgeW; pj.wdst[1] = edgeWT; pj.wK[1] = 64;  pj.wN[1] = 128; pj.wTot[1] = 64 * 128;
  pj.wsrc[2] = W1;    pj.wdst[2] = W1T;    pj.wK[2] = 128; pj.wN[2] = 256; pj.wTot[2] = 3 * 128 * 256;
  pj.wsrc[3] = W2;    pj.wdst[3] = W2T;    pj.wK[3] = 256; pj.wN[3] = 128; pj.wTot[3] = 3 * 256 * 128;
  pj.wsrc[4] = linW;  pj.wdst[4] = linWT;  pj.wK[4] = 128; pj.wN[4] = 112; pj.wTot[4] = 128 * 112;
  pj.bsrc[0] = nodeb; pj.bdst[0] = nodebf; pj.blen[0] = 128;
  pj.bsrc[1] = edgeb; pj.bdst[1] = edgebf; pj.blen[1] = 128;
  pj.bsrc[2] = b1;    pj.bdst[2] = b1f;    pj.blen[2] = 3 * 256;
  pj.bsrc[3] = b2;    pj.bdst[3] = b2f_;   pj.blen[3] = 3 * 128;
  pj.bsrc[4] = eps;   pj.bdst[4] = epsf;   pj.blen[4] = 3;
  pj.bsrc[5] = linb;  pj.bdst[5] = linbf;  pj.blen[5] = 112;
  int grand = 0;
  for (int g = 0; g < 5; ++g) grand += pj.wTot[g];
  for (int g = 0; g < 6; ++g) grand += pj.blen[g];
  prep_kernel<<<(grand + 255) / 256, 256, 0, stream>>>(pj, flag, grand);

  int eb = (ne + 255) / 256;
  int nb = (nn + 255) / 256;
  deg_kernel<<<eb, 256, 0, stream>>>(eidx + ne, deg, ne);
  scanA_kernel<<<nb, 256, 0, stream>>>(deg, rowptr, invdeg, btot, nn);
  scanC_kernel<<<nb, 256, 0, stream>>>(rowptr, btot, nn, ne);
  fill_kernel<<<eb, 256, 0, stream>>>(eidx, eidx + ne, rowptr, fillc, csr, ne);

  sattr_gather_kernel<<<(nn + 3) / 4, 256, 0, stream>>>(eattr, rowptr, csr, sattr, nn, flag);

  int gb = (nn + 63) / 64;
  gemm_kernel<128, 128, 0, 3><<<gb, 128, 0, stream>>>(x_in, nodeWT, nodebf, xcur, nn, flag, nullptr, nullptr);
  gemm_kernel<64, 128, 0, 2><<<gb, 128, 0, stream>>>(sattr, edgeWT, edgebf, seab, nn, flag, invdeg, deg);

  for (int l = 0; l < 3; ++l) {
    agg_kernel<<<(nn + 3) / 4, 256, 0, stream>>>(xcur, rowptr, csr, invdeg, seab, epsf, l, h0, nn);
    gemm_kernel<128, 256, 1, 0><<<gb, 128, 0, stream>>>(h0, W1T + (size_t)l * 128 * 256,
                                                        b1f + l * 256, tbuf, nn, flag, nullptr, nullptr);
    gemm_kernel<256, 128, 1, 0><<<gb, 128, 0, stream>>>(tbuf, W2T + (size_t)l * 256 * 128,
                                                        b2f_ + l * 128, xcur, nn, flag, nullptr, nullptr);
  }
  gemm_kernel<128, 112, 0, 1><<<gb, 128, 0, stream>>>(xcur, linWT, linbf, d_out, nn, flag, nullptr, nullptr);
}